// Round 7
// baseline (81.335 us; speedup 1.0000x reference)
//
#include <hip/hip_runtime.h>
#include <hip/hip_bf16.h>

#define NN   2048
#define DDIM 128
#define HH   8
#define DHH  16
#define NEDGE 65536
#define FFN  512
#define EPSV 1e-5f
#define CAP  256

typedef const float* fp_c;

// int64 vs int32 index layout: int64 values < 2048 have all-zero odd words.
__device__ __forceinline__ bool idx64(const int* src) {
    return (src[1] | src[3] | src[5] | src[7] | src[9] | src[11]) == 0;
}

// ================= fused prep + QKV =================
// blocks 0..255: QKV GEMM rows 8b..8b+7 (ROWS=8).
// blocks 256..383: prep (clear bitmap 512KB + ewin 2MB, edge-bias mini-GEMM).
__global__ __launch_bounds__(512) void k_pq(float* Qf, float* Kf, float* Vf, fp_c x,
                                            fp_c Wq, fp_c bq, fp_c Wk, fp_c bk, fp_c Wv, fp_c bv,
                                            int* ewin, unsigned* bm, float* eb,
                                            const int* src, const int* dst,
                                            fp_c edge_feat, fp_c We, fp_c be) {
    int b = blockIdx.x;
    int t = threadIdx.x;
    if (b < 256) {
        __shared__ float sx[8][DDIM];
        __shared__ float redq[4][8][DDIM];
        __shared__ float redk[4][8][DDIM];
        __shared__ float redv[4][8][DDIM];
        int r0 = b * 8;
        int c = t & 127;
        int ks = t >> 7;
        sx[t >> 7][t & 127]       = x[r0 * DDIM + t];
        sx[4 + (t >> 7)][t & 127] = x[r0 * DDIM + 512 + t];
        __syncthreads();
        float aq[8], ak[8], av[8];
#pragma unroll
        for (int r = 0; r < 8; r++) { aq[r] = 0; ak[r] = 0; av[r] = 0; }
        int kbeg = ks * 32;
#pragma unroll 8
        for (int k = kbeg; k < kbeg + 32; k++) {
            float wq = Wq[k * DDIM + c];
            float wk = Wk[k * DDIM + c];
            float wv = Wv[k * DDIM + c];
#pragma unroll
            for (int r = 0; r < 8; r++) {
                float xv = sx[r][k];
                aq[r] += xv * wq; ak[r] += xv * wk; av[r] += xv * wv;
            }
        }
#pragma unroll
        for (int r = 0; r < 8; r++) {
            redq[ks][r][c] = aq[r];
            redk[ks][r][c] = ak[r];
            redv[ks][r][c] = av[r];
        }
        __syncthreads();
        int rr = t >> 7, cc = t & 127;
        float vq0 = 0, vk0 = 0, vv0 = 0, vq1 = 0, vk1 = 0, vv1 = 0;
#pragma unroll
        for (int s = 0; s < 4; s++) {
            vq0 += redq[s][rr][cc];     vk0 += redk[s][rr][cc];     vv0 += redv[s][rr][cc];
            vq1 += redq[s][rr + 4][cc]; vk1 += redk[s][rr + 4][cc]; vv1 += redv[s][rr + 4][cc];
        }
        float vbq = bq[cc], vbk = bk[cc], vbv = bv[cc];
        Qf[(r0 + rr) * DDIM + cc]     = (vq0 + vbq) * 0.25f;
        Kf[(r0 + rr) * DDIM + cc]     = vk0 + vbk;
        Vf[(r0 + rr) * DDIM + cc]     = vv0 + vbv;
        Qf[(r0 + rr + 4) * DDIM + cc] = (vq1 + vbq) * 0.25f;
        Kf[(r0 + rr + 4) * DDIM + cc] = vk1 + vbk;
        Vf[(r0 + rr + 4) * DDIM + cc] = vv1 + vbv;
    } else {
        __shared__ float sWe[80];
        __shared__ float sbe[8];
        if (t < 80) sWe[t] = We[t];
        if (t < 8)  sbe[t] = be[t];
        __syncthreads();
        int u = (b - 256) * 512 + t;
        if (u < NN * 64 / 4) ((int4*)bm)[u] = make_int4(0, 0, 0, 0);
        // clear ewin: 2MB = 131072 int4, u covers 65536 -> two stores
        ((int4*)ewin)[u]         = make_int4(0, 0, 0, 0);
        ((int4*)ewin)[u + 65536] = make_int4(0, 0, 0, 0);
        if (u < NEDGE) {
            float ef[10];
#pragma unroll
            for (int k = 0; k < 10; k++) ef[k] = edge_feat[u * 10 + k];
#pragma unroll
            for (int h = 0; h < 8; h++) {
                float a = sbe[h];
#pragma unroll
                for (int k = 0; k < 10; k++) a += ef[k] * sWe[k * 8 + h];
                eb[u * 8 + h] = a;
            }
        }
    }
}

// ---------------- scatter pass 1: adjacency bitmap only ----------------
__global__ __launch_bounds__(512) void k_scatter(unsigned* bm, const int* src, const int* dst) {
    int t = blockIdx.x * blockDim.x + threadIdx.x;
    bool is64 = idx64(src);
    if (t < NEDGE) {
        int s = is64 ? src[2 * t] : src[t];
        int d = is64 ? dst[2 * t] : dst[t];
        atomicOr(&bm[s * 64 + (d >> 5)], 1u << (d & 31));
        atomicOr(&bm[d * 64 + (s >> 5)], 1u << (s & 31));
    } else if (t < NEDGE + NN) {
        int i = t - NEDGE;
        atomicOr(&bm[i * 64 + (i >> 5)], 1u << (i & 31));
    }
}

// ---------------- scatter pass 2: edge -> rank slot, max(e+1) = last-wins ----------------
__global__ __launch_bounds__(512) void k_rank(int* ewin, const unsigned* bm,
                                              const int* src, const int* dst) {
    int e = blockIdx.x * blockDim.x + threadIdx.x;
    if (e >= NEDGE) return;
    bool is64 = idx64(src);
    int s = is64 ? src[2 * e] : src[e];
    int d = is64 ? dst[2 * e] : dst[e];
    const unsigned* row = bm + s * 64;
    int dw = d >> 5;
    int rank = __popc(row[dw] & ((1u << (d & 31)) - 1u));
    for (int w = 0; w < dw; w++) rank += __popc(row[w]);
    atomicMax(&ewin[s * CAP + rank], e + 1);
}

// ---------------- sparse masked attention: 256 threads (4 waves) per row ----------------
__global__ __launch_bounds__(256) void k_attn(float* attn_out, const float* Qf, const float* Kf,
                                              const float* Vf, const int* ewin, const float* eb,
                                              const unsigned* bm) {
    __shared__ float qrow[DDIM];
    __shared__ int   lj[CAP + 8];
    __shared__ int   lev[CAP + 8];
    __shared__ float sc[CAP + 8][HH];
    __shared__ float hinv[HH];
    __shared__ float redpv[2][DDIM];
    __shared__ int   scnt;
    int i = blockIdx.x;
    int t = threadIdx.x;
    if (t < 128) qrow[t] = Qf[i * DDIM + t];

    // phase 1 (wave 0): bitmap -> compacted neighbor list (ascending j)
    if (t < 64) {
        unsigned word = bm[i * 64 + t];
        int pc = __popc(word);
        int x = pc;
#pragma unroll
        for (int off = 1; off < 64; off <<= 1) {
            int y = __shfl_up(x, off);
            if (t >= off) x += y;
        }
        int cnt = __shfl(x, 63);
        if (cnt > CAP - 8) cnt = CAP - 8;
        int idx = x - pc;
        unsigned w = word;
        while (w && idx < CAP) {
            int bpos = __ffs(w) - 1;
            lj[idx++] = (t << 5) + bpos;
            w &= w - 1;
        }
        if (t < 8) lj[cnt + t] = 0;  // pad slots
        if (t == 0) scnt = cnt;
    }
    __syncthreads();
    int cnt = scnt;
    int cnt8 = (cnt + 7) & ~7;
    // rank-indexed bias id: contiguous, coalesced read
    if (t < cnt8) lev[t] = (t < cnt) ? (ewin[i * CAP + t] - 1) : -1;
    __syncthreads();

    // phase 2: scores — 32 neighbor slots x 8 heads in parallel
    int h = t & 7;
    int nsl = t >> 3;
    const float4* q4 = (const float4*)(qrow + h * DHH);
    float4 q0 = q4[0], q1 = q4[1], q2 = q4[2], q3 = q4[3];
    for (int n = nsl; n < cnt8; n += 32) {
        int j = lj[n];
        const float4* k4 = (const float4*)(Kf + j * DDIM + h * DHH);
        float4 k0 = k4[0], k1 = k4[1], k2 = k4[2], k3 = k4[3];
        float s = q0.x * k0.x + q0.y * k0.y + q0.z * k0.z + q0.w * k0.w
                + q1.x * k1.x + q1.y * k1.y + q1.z * k1.z + q1.w * k1.w
                + q2.x * k2.x + q2.y * k2.y + q2.z * k2.z + q2.w * k2.w
                + q3.x * k3.x + q3.y * k3.y + q3.z * k3.z + q3.w * k3.w;
        int ev = lev[n];
        if (ev >= 0) s += eb[ev * 8 + h];
        sc[n][h] = s;
    }
    __syncthreads();

    // phase 3: per-head softmax — 32 threads per head
    {
        int hh = t >> 5;
        int sub = t & 31;
        float m = -1e30f;
        for (int n = sub; n < cnt; n += 32) m = fmaxf(m, sc[n][hh]);
#pragma unroll
        for (int off = 1; off < 32; off <<= 1) m = fmaxf(m, __shfl_xor(m, off));
        float ssum = 0.f;
        for (int n = sub; n < cnt; n += 32) {
            float e = __expf(sc[n][hh] - m);
            sc[n][hh] = e;
            ssum += e;
        }
#pragma unroll
        for (int off = 1; off < 32; off <<= 1) ssum += __shfl_xor(ssum, off);
        if (sub == 0) hinv[hh] = 1.0f / ssum;
    }
    // zero pad rows (<=7 rows x 8 heads, threads 0..63)
    if (t < 64) {
        int p = cnt + (t >> 3);
        if (p < cnt8) sc[p][t & 7] = 0.f;
    }
    __syncthreads();

    // phase 4: PV — neighbors split across 2 groups of 128 threads
    {
        int g = t >> 7, c = t & 127, h2 = c >> 4;
        float a = 0.f;
#pragma unroll 4
        for (int n = g; n < cnt8; n += 2)
            a += sc[n][h2] * Vf[lj[n] * DDIM + c];
        redpv[g][c] = a;
    }
    __syncthreads();
    if (t < 128)
        attn_out[i * DDIM + t] = (redpv[0][t] + redpv[1][t]) * hinv[t >> 4];
}

// ================= fused tail: Wo+LN1 -> FFN1 -> FFN2+LN2, ROWS=8 =================
__global__ __launch_bounds__(512) void k_tail(float* out, const float* ain,
                                              fp_c Wo, fp_c bo, fp_c node, fp_c g1, fp_c b1,
                                              fp_c W1, fp_c bf1, fp_c W2, fp_c bf2,
                                              fp_c g2, fp_c b2) {
    __shared__ float sa[8][DDIM];
    __shared__ float red[4][8][DDIM];
    __shared__ float x1ld[8][DDIM];
    __shared__ float sh[8][FFN];
    __shared__ float4 sc4[8];
    int t = threadIdx.x;
    int r0 = blockIdx.x * 8;
    int c = t & 127;
    int ks = t >> 7;
    int rr = t >> 7, cc = t & 127;
    sa[t >> 7][t & 127]       = ain[r0 * DDIM + t];
    sa[4 + (t >> 7)][t & 127] = ain[r0 * DDIM + 512 + t];
    __syncthreads();

    // phase A: Wo proj (K-split 4) + bias + residual + LN1 -> x1ld
    {
        float acc[8] = {0, 0, 0, 0, 0, 0, 0, 0};
        int kbeg = ks * 32;
#pragma unroll 8
        for (int k = kbeg; k < kbeg + 32; k++) {
            float w = Wo[k * DDIM + c];
#pragma unroll
            for (int r = 0; r < 8; r++) acc[r] += sa[r][k] * w;
        }
#pragma unroll
        for (int r = 0; r < 8; r++) red[ks][r][c] = acc[r];
        __syncthreads();
        float bov = bo[cc];
        float val0 = red[0][rr][cc] + red[1][rr][cc] + red[2][rr][cc] + red[3][rr][cc]
                   + bov + node[(r0 + rr) * DDIM + cc];
        float val1 = red[0][rr + 4][cc] + red[1][rr + 4][cc] + red[2][rr + 4][cc] + red[3][rr + 4][cc]
                   + bov + node[(r0 + rr + 4) * DDIM + cc];
        float4 v = make_float4(val0, val0 * val0, val1, val1 * val1);
#pragma unroll
        for (int off = 32; off >= 1; off >>= 1) {
            v.x += __shfl_down(v.x, off);
            v.y += __shfl_down(v.y, off);
            v.z += __shfl_down(v.z, off);
            v.w += __shfl_down(v.w, off);
        }
        if ((t & 63) == 0) sc4[t >> 6] = v;
        __syncthreads();
        float gv = g1[cc], bv = b1[cc];
        {
            float sum = sc4[2 * rr].x + sc4[2 * rr + 1].x;
            float sq  = sc4[2 * rr].y + sc4[2 * rr + 1].y;
            float mu = sum * (1.0f / DDIM);
            float var = sq * (1.0f / DDIM) - mu * mu;
            x1ld[rr][cc] = (val0 - mu) * rsqrtf(var + EPSV) * gv + bv;
        }
        {
            float sum = sc4[2 * rr].z + sc4[2 * rr + 1].z;
            float sq  = sc4[2 * rr].w + sc4[2 * rr + 1].w;
            float mu = sum * (1.0f / DDIM);
            float var = sq * (1.0f / DDIM) - mu * mu;
            x1ld[rr + 4][cc] = (val1 - mu) * rsqrtf(var + EPSV) * gv + bv;
        }
    }
    __syncthreads();

    // phase B: hidden = relu(x1 @ W1 + bf1), column t of 512
    {
        float acc[8] = {0, 0, 0, 0, 0, 0, 0, 0};
#pragma unroll 4
        for (int k = 0; k < DDIM; k++) {
            float w = W1[k * FFN + t];
#pragma unroll
            for (int r = 0; r < 8; r++) acc[r] += x1ld[r][k] * w;
        }
        float bb = bf1[t];
#pragma unroll
        for (int r = 0; r < 8; r++) sh[r][t] = fmaxf(acc[r] + bb, 0.f);
    }
    __syncthreads();

    // phase C: ffn2 (K-split 4 over 512) + bias + residual + LN2 -> out
    {
        float acc[8] = {0, 0, 0, 0, 0, 0, 0, 0};
        int kbeg = ks * 128;
#pragma unroll 8
        for (int k = kbeg; k < kbeg + 128; k++) {
            float w = W2[k * DDIM + c];
#pragma unroll
            for (int r = 0; r < 8; r++) acc[r] += sh[r][k] * w;
        }
#pragma unroll
        for (int r = 0; r < 8; r++) red[ks][r][c] = acc[r];
        __syncthreads();
        float bv2 = bf2[cc];
        float val0 = red[0][rr][cc] + red[1][rr][cc] + red[2][rr][cc] + red[3][rr][cc]
                   + bv2 + x1ld[rr][cc];
        float val1 = red[0][rr + 4][cc] + red[1][rr + 4][cc] + red[2][rr + 4][cc] + red[3][rr + 4][cc]
                   + bv2 + x1ld[rr + 4][cc];
        float4 v = make_float4(val0, val0 * val0, val1, val1 * val1);
#pragma unroll
        for (int off = 32; off >= 1; off >>= 1) {
            v.x += __shfl_down(v.x, off);
            v.y += __shfl_down(v.y, off);
            v.z += __shfl_down(v.z, off);
            v.w += __shfl_down(v.w, off);
        }
        if ((t & 63) == 0) sc4[t >> 6] = v;
        __syncthreads();
        float gv = g2[cc], bv = b2[cc];
        {
            float sum = sc4[2 * rr].x + sc4[2 * rr + 1].x;
            float sq  = sc4[2 * rr].y + sc4[2 * rr + 1].y;
            float mu = sum * (1.0f / DDIM);
            float var = sq * (1.0f / DDIM) - mu * mu;
            out[(r0 + rr) * DDIM + cc] = (val0 - mu) * rsqrtf(var + EPSV) * gv + bv;
        }
        {
            float sum = sc4[2 * rr].z + sc4[2 * rr + 1].z;
            float sq  = sc4[2 * rr].w + sc4[2 * rr + 1].w;
            float mu = sum * (1.0f / DDIM);
            float var = sq * (1.0f / DDIM) - mu * mu;
            out[(r0 + rr + 4) * DDIM + cc] = (val1 - mu) * rsqrtf(var + EPSV) * gv + bv;
        }
    }
}

extern "C" void kernel_launch(void* const* d_in, const int* in_sizes, int n_in,
                              void* d_out, int out_size, void* d_ws, size_t ws_size,
                              hipStream_t stream) {
    fp_c node = (fp_c)d_in[0];
    fp_c edge_feat = (fp_c)d_in[1];
    const int* src = (const int*)d_in[2];
    const int* dst = (const int*)d_in[3];
    fp_c Wq = (fp_c)d_in[4];  fp_c bq = (fp_c)d_in[5];
    fp_c Wk = (fp_c)d_in[6];  fp_c bk = (fp_c)d_in[7];
    fp_c Wv = (fp_c)d_in[8];  fp_c bv = (fp_c)d_in[9];
    fp_c Wo = (fp_c)d_in[10]; fp_c bo = (fp_c)d_in[11];
    fp_c We = (fp_c)d_in[12]; fp_c be = (fp_c)d_in[13];
    fp_c g1 = (fp_c)d_in[14]; fp_c b1n = (fp_c)d_in[15];
    fp_c g2 = (fp_c)d_in[16]; fp_c b2n = (fp_c)d_in[17];
    fp_c W1 = (fp_c)d_in[18]; fp_c bf1 = (fp_c)d_in[19];
    fp_c W2 = (fp_c)d_in[20]; fp_c bf2 = (fp_c)d_in[21];

    char* ws = (char*)d_ws;
    int* ewin     = (int*)ws;      ws += (size_t)NN * CAP * 4;   // 2 MB
    unsigned* bm  = (unsigned*)ws; ws += (size_t)NN * 64 * 4;    // 512 KB
    float* eb     = (float*)ws;    ws += (size_t)NEDGE * 8 * 4;  // 2 MB
    float* Qf     = (float*)ws;    ws += (size_t)NN * DDIM * 4;
    float* Kf     = (float*)ws;    ws += (size_t)NN * DDIM * 4;
    float* Vf     = (float*)ws;    ws += (size_t)NN * DDIM * 4;
    float* attn_o = (float*)ws;    ws += (size_t)NN * DDIM * 4;

    k_pq<<<384, 512, 0, stream>>>(Qf, Kf, Vf, node, Wq, bq, Wk, bk, Wv, bv,
                                  ewin, bm, eb, src, dst, edge_feat, We, be);
    k_scatter<<<(NEDGE + NN + 511) / 512, 512, 0, stream>>>(bm, src, dst);
    k_rank<<<NEDGE / 512, 512, 0, stream>>>(ewin, bm, src, dst);
    k_attn<<<NN, 256, 0, stream>>>(attn_o, Qf, Kf, Vf, ewin, eb, bm);
    k_tail<<<NN / 8, 512, 0, stream>>>((float*)d_out, attn_o, Wo, bo, node, g1, b1n,
                                       W1, bf1, W2, bf2, g2, b2n);
}